// Round 16
// baseline (221.185 us; speedup 1.0000x reference)
//
#include <hip/hip_runtime.h>
#include <hip/hip_bf16.h>

typedef __attribute__((ext_vector_type(8))) short short8;
typedef __attribute__((ext_vector_type(4))) float f32x4;
typedef unsigned short us;

#define MFMA16(a,b,c) __builtin_amdgcn_mfma_f32_16x16x32_bf16((a),(b),(c),0,0,0)
#define LOG2E 1.4426950408889634f

static __device__ __forceinline__ us bf16r(float x){
  unsigned u = __builtin_bit_cast(unsigned, x);
  u = u + 0x7fffu + ((u >> 16) & 1u);
  return (us)(u >> 16);
}
static __device__ __forceinline__ unsigned cvtpk(float a, float b){
  unsigned r; asm("v_cvt_pk_bf16_f32 %0, %1, %2" : "=v"(r) : "v"(a), "v"(b)); return r;
}
static __device__ __forceinline__ short8 cvt8(float4 a, float4 b){
  uint4 u; u.x = cvtpk(a.x, a.y); u.y = cvtpk(a.z, a.w);
  u.z = cvtpk(b.x, b.y); u.w = cvtpk(b.z, b.w);
  return __builtin_bit_cast(short8, u);
}
static __device__ __forceinline__ float b2f(us h){
  return __builtin_bit_cast(float, (unsigned)h << 16);
}
static __device__ __forceinline__ float PKLO(unsigned u){
  return __builtin_bit_cast(float, u << 16);
}
static __device__ __forceinline__ float PKHI(unsigned u){
  return __builtin_bit_cast(float, u & 0xffff0000u);
}
static __device__ __forceinline__ float exp2fast(float x){
  float r; asm("v_exp_f32 %0, %1" : "=v"(r) : "v"(x)); return r;
}
static __device__ __forceinline__ float rcpfast(float x){
  float r; asm("v_rcp_f32 %0, %1" : "=v"(r) : "v"(x)); return r;
}
static __device__ __forceinline__ float fractfast(float x){
  float r; asm("v_fract_f32 %0, %1" : "=v"(r) : "v"(x)); return r;
}
static __device__ __forceinline__ float sigm(float y){
  return rcpfast(1.f + exp2fast(-y));
}
static __device__ __forceinline__ unsigned bperm(int lanebyte, unsigned v){
  return (unsigned)__builtin_amdgcn_ds_bpermute(lanebyte, (int)v);
}
static __device__ __forceinline__ float sxor(float v, int m){
  return __shfl_xor(v, m);
}

// ---------------- pos_emb [64d][64n] fp32 -> peT [64n][64d] bf16, pre-scaled by log2(e) ----
__global__ __launch_bounds__(256)
void transpose_pe(const float* __restrict__ pe, us* __restrict__ peT){
  const int t = threadIdx.x;
  const int n = t & 63, dq = t >> 6;
#pragma unroll
  for (int j = 0; j < 16; ++j){
    const int d = dq * 16 + j;
    peT[n * 64 + d] = bf16r(pe[d * 64 + n] * LOG2E);
  }
}

// ---------------- V bf16 [4096][1024] -> VT bf16 [b][h][64d][1024s] ----------------
__global__ __launch_bounds__(256)
void transpose_v(const us* __restrict__ Vb, us* __restrict__ VT){
  __shared__ __align__(16) us tile[64 * 72];
  const int t = threadIdx.x;
  const int stile = blockIdx.x & 15;
  const int bh = blockIdx.x >> 4;
  const int b = bh >> 4, h = bh & 15;
  const int s0 = stile << 6;
#pragma unroll
  for (int c = 0; c < 2; ++c){
    const int idx = t + (c << 8);
    const int sr = idx >> 3, cw = idx & 7;
    *(short8*)&tile[sr * 72 + cw * 8] =
        *(const short8*)(Vb + ((size_t)(b * 1024 + s0 + sr)) * 1024 + h * 64 + cw * 8);
  }
  __syncthreads();
#pragma unroll
  for (int c = 0; c < 2; ++c){
    const int idx = t + (c << 8);
    const int dr = idx >> 3, sw = idx & 7;
    short8 o;
#pragma unroll
    for (int j = 0; j < 8; ++j) o[j] = (short)tile[(sw * 8 + j) * 72 + dr];
    *(short8*)(VT + ((size_t)(bh * 64 + dr)) * 1024 + s0 + sw * 8) = o;
  }
}

// ---------------- GEMM: C[4096][1024] = A[4096][1024] @ W[1024][1024]^T + bias ----------
template<bool A_BF16, bool OUT_BF16>
__global__ __launch_bounds__(256)
void gemm3(const void* __restrict__ Av0, const void* __restrict__ Av1, const void* __restrict__ Av2,
           const float* __restrict__ W0, const float* __restrict__ W1, const float* __restrict__ W2,
           const float* __restrict__ bp0, const float* __restrict__ bp1, const float* __restrict__ bp2,
           void* __restrict__ O0, void* __restrict__ O1, void* __restrict__ O2){
  __shared__ __align__(16) us Al[128 * 64];
  __shared__ __align__(16) us Bl[128 * 64];
  const int sel = blockIdx.y;
  const void* Av   = sel == 0 ? Av0 : (sel == 1 ? Av1 : Av2);
  const float* Wm  = sel == 0 ? W0  : (sel == 1 ? W1  : W2);
  const float* bias = sel == 0 ? bp0 : (sel == 1 ? bp1 : bp2);
  void* Ov         = sel == 0 ? O0  : (sel == 1 ? O1  : O2);
  const int tid = threadIdx.x;
  const int bm = blockIdx.x & 31, bn = blockIdx.x >> 5;
  const int m0 = bm << 7, n0 = bn << 7;
  const int w = tid >> 6, l = tid & 63;
  const int lr = l & 15, lg = l >> 4;
  const int wm = (w & 1) << 6, wn = (w >> 1) << 6;
  int srow[4], scol[4], sdst[4];
#pragma unroll
  for (int c = 0; c < 4; ++c){
    const int idx = tid + (c << 8);
    const int r = idx >> 3, cw = idx & 7;
    srow[c] = r; scol[c] = cw << 3;
    sdst[c] = r * 64 + ((cw << 3) ^ ((r & 7) << 3));
  }
  const int swz = (lr & 7) << 3;
  f32x4 acc[4][4];
#pragma unroll
  for (int i = 0; i < 4; ++i)
#pragma unroll
    for (int j = 0; j < 4; ++j) acc[i][j] = (f32x4){0.f, 0.f, 0.f, 0.f};

  auto ldA = [&](int c, int k) -> short8 {
    if constexpr (A_BF16){
      return *(const short8*)((const us*)Av + (size_t)(m0 + srow[c]) * 1024 + k + scol[c]);
    } else {
      const float* p = (const float*)Av + (size_t)(m0 + srow[c]) * 1024 + k + scol[c];
      return cvt8(*(const float4*)p, *(const float4*)(p + 4));
    }
  };
  auto ldW = [&](int c, int k) -> short8 {
    const float* p = Wm + (size_t)(n0 + srow[c]) * 1024 + k + scol[c];
    return cvt8(*(const float4*)p, *(const float4*)(p + 4));
  };

  short8 av[4], bv[4];
#pragma unroll
  for (int c = 0; c < 4; ++c){ av[c] = ldA(c, 0); bv[c] = ldW(c, 0); }

  for (int k0 = 0; k0 < 1024; k0 += 64){
    __syncthreads();
#pragma unroll
    for (int c = 0; c < 4; ++c){
      *(short8*)&Al[sdst[c]] = av[c];
      *(short8*)&Bl[sdst[c]] = bv[c];
    }
    __syncthreads();
    if (k0 < 960){
#pragma unroll
      for (int c = 0; c < 4; ++c){ av[c] = ldA(c, k0 + 64); bv[c] = ldW(c, k0 + 64); }
    }
#pragma unroll
    for (int ks = 0; ks < 2; ++ks){
      short8 af[4], bfv[4];
#pragma unroll
      for (int mt = 0; mt < 4; ++mt)
        af[mt] = *(const short8*)&Al[(wm + mt * 16 + lr) * 64 + (((ks << 5) + (lg << 3)) ^ swz)];
#pragma unroll
      for (int nt = 0; nt < 4; ++nt)
        bfv[nt] = *(const short8*)&Bl[(wn + nt * 16 + lr) * 64 + (((ks << 5) + (lg << 3)) ^ swz)];
#pragma unroll
      for (int mt = 0; mt < 4; ++mt)
#pragma unroll
        for (int nt = 0; nt < 4; ++nt)
          acc[mt][nt] = MFMA16(af[mt], bfv[nt], acc[mt][nt]);
    }
  }
  float bb[4];
#pragma unroll
  for (int nt = 0; nt < 4; ++nt) bb[nt] = bias[n0 + wn + nt * 16 + lr];
#pragma unroll
  for (int mt = 0; mt < 4; ++mt)
#pragma unroll
    for (int nt = 0; nt < 4; ++nt)
#pragma unroll
      for (int r = 0; r < 4; ++r){
        const size_t m = m0 + wm + mt * 16 + lg * 4 + r;
        const size_t n = n0 + wn + nt * 16 + lr;
        const float vv = acc[mt][nt][r] + bb[nt];
        if (OUT_BF16) ((us*)Ov)[m * 1024 + n] = bf16r(vv);
        else          ((float*)Ov)[m * 1024 + n] = vv;
      }
}

// ---------------- fused CoPE attention v14b: register-resident, swapped-operand QK ------
// mfma(K,Q) -> S^T: lane owns q=l&15, k=(l>>4)*4+r. Logits/gates/P stay in registers;
// cross-wave only for per-q gate totals (256B LDS) and final O reduce. 4-5 barriers.
__global__ __launch_bounds__(256)
void cope_attn_v14(const us* __restrict__ Qb, const us* __restrict__ Kb,
                   const us* __restrict__ VT, const us* __restrict__ peT,
                   us* __restrict__ Ob){
  __shared__ __align__(16) char smem[21248];
  unsigned* pkt  = (unsigned*)smem;             // [16][64] packed {li, dli}
  us*      li16  = (us*)(smem + 4096);          // temp, overlaps opart
  float*   opart = (float*)(smem + 4096);       // [4][16][64]
  float*   wtot  = (float*)(smem + 20480);      // [2][4][16]
  float*   dsumL = (float*)(smem + 20992);      // [4][16]

  const int tid = threadIdx.x;
  const int w = tid >> 6, l = tid & 63;
  const int lr = l & 15, lg = l >> 4;
  const int wg = ((blockIdx.x & 7) << 9) | (blockIdx.x >> 3);  // XCD swizzle
  const int qt = wg & 63;
  const int bh = wg >> 6;
  const int b = bh >> 4, h = bh & 15;
  const int q0 = qt << 4;
  const us* Qh = Qb + ((size_t)(b * 1024 + q0)) * 1024 + h * 64;
  const us* Kh = Kb + ((size_t)(b * 1024)) * 1024 + h * 64;
  const us* Vh = VT + ((size_t)bh) * 64 * 1024;
  const float QSC = 0.125f * LOG2E;
  const f32x4 zf = (f32x4){0.f, 0.f, 0.f, 0.f};

  // Q fragments (row=lr, d=lg*8..): A-operand for li, B-operand for swapped QK
  const short8 bq0 = *(const short8*)(Qh + (size_t)lr * 1024 + lg * 8);
  const short8 bq1 = *(const short8*)(Qh + (size_t)lr * 1024 + 32 + lg * 8);

  // setup: li[q][n] = (Q.pe)*log2e  -> packed {li, li[n+1]-li[n]} table in LDS
  {
    f32x4 a = zf;
    const short8 p0 = *(const short8*)(peT + (size_t)(w * 16 + lr) * 64 + lg * 8);
    const short8 p1 = *(const short8*)(peT + (size_t)(w * 16 + lr) * 64 + 32 + lg * 8);
    a = MFMA16(bq0, p0, a);
    a = MFMA16(bq1, p1, a);
#pragma unroll
    for (int r = 0; r < 4; ++r) li16[(lg * 4 + r) * 64 + w * 16 + lr] = bf16r(a[r]);
  }
  __syncthreads();
  unsigned myPk[4];
#pragma unroll
  for (int i = 0; i < 4; ++i){
    const int e = tid * 4 + i;
    const int qq = e >> 6, n = e & 63;
    const us lov = li16[qq * 64 + n];
    const us hiv = (n < 63) ? li16[qq * 64 + n + 1] : lov;
    myPk[i] = (unsigned)lov | ((unsigned)bf16r(b2f(hiv) - b2f(lov)) << 16);
  }
  __syncthreads();   // li16 reads complete before pkt overwrites (aliased region is distinct but be safe)
#pragma unroll
  for (int i = 0; i < 4; ++i) pkt[tid * 4 + i] = myPk[i];
  __syncthreads();
  const unsigned* pq = pkt + (lr << 6);     // this lane's q-row of the table
  const float li63q = PKLO(pq[63]);

  f32x4 oacc[4];
#pragma unroll
  for (int dt = 0; dt < 4; ++dt) oacc[dt] = zf;
  float esum = 0.f;
  float carryq = 0.f;
  bool clamp0 = false;

#pragma unroll
  for (int c = 1; c >= 0; --c){
    const int kwbase = (c << 9) + (w << 7);
    unsigned ypk[8][2], gpk[8][2];
    // ---- QK (registers only): S^T via swapped operands ----
#pragma unroll
    for (int t = 0; t < 8; ++t){
      const us* Kp = Kh + (size_t)(kwbase + t * 16 + lr) * 1024 + lg * 8;
      const short8 a0 = *(const short8*)Kp;
      const short8 a1 = *(const short8*)(Kp + 32);
      f32x4 s = zf;
      s = MFMA16(a0, bq0, s);
      s = MFMA16(a1, bq1, s);
      ypk[t][0] = cvtpk(s[0] * QSC, s[1] * QSC);
      ypk[t][1] = cvtpk(s[2] * QSC, s[3] * QSC);
    }
    const bool fullpath = (c == 1) || (!clamp0);
    if (fullpath){
      // ---- gates + per-q wave totals ----
      float ltot = 0.f;
#pragma unroll
      for (int t = 0; t < 8; ++t){
        const float g0 = sigm(PKLO(ypk[t][0])), g1 = sigm(PKHI(ypk[t][0]));
        const float g2 = sigm(PKLO(ypk[t][1])), g3 = sigm(PKHI(ypk[t][1]));
        gpk[t][0] = cvtpk(g0, g1); gpk[t][1] = cvtpk(g2, g3);
        ltot += (g0 + g1) + (g2 + g3);
      }
      float t1 = ltot + sxor(ltot, 16);
      const float Twq = t1 + sxor(t1, 32);
      if (l < 16) wtot[c * 64 + w * 16 + l] = Twq;
      __syncthreads();
      const float tw0 = wtot[c * 64 + 0 + lr];
      const float tw1 = wtot[c * 64 + 16 + lr];
      const float tw2 = wtot[c * 64 + 32 + lr];
      const float tw3 = wtot[c * 64 + 48 + lr];
      float shw = 0.f;
      if (w == 0) shw = tw1 + tw2 + tw3;
      else if (w == 1) shw = tw2 + tw3;
      else if (w == 2) shw = tw3;
      const float carry_in = shw + (c == 0 ? carryq : 0.f);
      if (c == 1){
        carryq = (tw0 + tw1) + (tw2 + tw3);
        clamp0 = __all(carryq >= 63.f);
      }
      // ---- pass2 A: tile sums / same-tile lane-group suffix / tile suffix ----
      float sT[8], sufg[8], tsuf[8];
#pragma unroll
      for (int t = 0; t < 8; ++t){
        const float g0 = PKLO(gpk[t][0]), g1 = PKHI(gpk[t][0]);
        const float g2 = PKLO(gpk[t][1]), g3 = PKHI(gpk[t][1]);
        const float st = (g0 + g1) + (g2 + g3);
        const float sa = sxor(st, 16);
        const float sb = sxor(st, 32);
        const float sc = sxor(sa, 32);
        sT[t] = st;
        sufg[t] = (lg == 0) ? (sa + sb + sc) : (lg == 1) ? (sb + sc) : (lg == 2) ? sa : 0.f;
        tsuf[t] = st + sa + sb + sc;    // tile total (for now)
      }
      float run = 0.f;
#pragma unroll
      for (int t = 7; t >= 0; --t){ const float tmp = tsuf[t]; tsuf[t] = run; run += tmp; }
      // ---- pass2 B: positions, li gather, exp2, pack P ----
      // position for elem r of tile t = carry_in + tsuf[t] + sufg[t] + (sT[t] - own-prefix)
      //   own inclusive suffix within lane elems: use exclusive prefix from g's
#pragma unroll
      for (int t = 0; t < 8; ++t){
        const float g0 = PKLO(gpk[t][0]), g1 = PKHI(gpk[t][0]);
        const float g2 = PKLO(gpk[t][1]);
        const float y0 = PKLO(ypk[t][0]), y1 = PKHI(ypk[t][0]);
        const float y2 = PKLO(ypk[t][1]), y3 = PKHI(ypk[t][1]);
        const float bbv = carry_in + tsuf[t] + sufg[t] + sT[t];
        float e0, e1, e2, e3;
        {
          const float p = __builtin_amdgcn_fmed3f(bbv, 0.f, 63.f);
          const unsigned pr = pq[(int)p];
          e0 = exp2fast(y0 + PKLO(pr) + fractfast(p) * PKHI(pr));
        }
        {
          const float p = __builtin_amdgcn_fmed3f(bbv - g0, 0.f, 63.f);
          const unsigned pr = pq[(int)p];
          e1 = exp2fast(y1 + PKLO(pr) + fractfast(p) * PKHI(pr));
        }
        {
          const float p = __builtin_amdgcn_fmed3f(bbv - (g0 + g1), 0.f, 63.f);
          const unsigned pr = pq[(int)p];
          e2 = exp2fast(y2 + PKLO(pr) + fractfast(p) * PKHI(pr));
        }
        {
          const float p = __builtin_amdgcn_fmed3f(bbv - ((g0 + g1) + g2), 0.f, 63.f);
          const unsigned pr = pq[(int)p];
          e3 = exp2fast(y3 + PKLO(pr) + fractfast(p) * PKHI(pr));
        }
        esum += (e0 + e1) + (e2 + e3);
        gpk[t][0] = cvtpk(e0, e1); gpk[t][1] = cvtpk(e2, e3);   // now P
      }
    } else {
      // ---- clamped chunk 0: pos==63 for all keys -> +li[63] uniformly ----
#pragma unroll
      for (int t = 0; t < 8; ++t){
        const float e0 = exp2fast(PKLO(ypk[t][0]) + li63q);
        const float e1 = exp2fast(PKHI(ypk[t][0]) + li63q);
        const float e2 = exp2fast(PKLO(ypk[t][1]) + li63q);
        const float e3 = exp2fast(PKHI(ypk[t][1]) + li63q);
        esum += (e0 + e1) + (e2 + e3);
        gpk[t][0] = cvtpk(e0, e1); gpk[t][1] = cvtpk(e2, e3);
      }
    }
    // ---- P redistribute (in-wave bpermute) + PV over this wave's k-range ----
    const int sa4 = (lr + ((lg & 1) << 5)) << 2;
    const int sb4 = sa4 + 64;
    const bool hi2 = ((lg >> 1) & 1) != 0;
#pragma unroll
    for (int u = 0; u < 4; ++u){
      const unsigned p0a = bperm(sa4, gpk[2 * u][0]),     p0b = bperm(sa4, gpk[2 * u + 1][0]);
      const unsigned p1a = bperm(sa4, gpk[2 * u][1]),     p1b = bperm(sa4, gpk[2 * u + 1][1]);
      const unsigned p2a = bperm(sb4, gpk[2 * u][0]),     p2b = bperm(sb4, gpk[2 * u + 1][0]);
      const unsigned p3a = bperm(sb4, gpk[2 * u][1]),     p3b = bperm(sb4, gpk[2 * u + 1][1]);
      uint4 af;
      af.x = hi2 ? p0b : p0a;
      af.y = hi2 ? p1b : p1a;
      af.z = hi2 ? p2b : p2a;
      af.w = hi2 ? p3b : p3a;
      const short8 pa = __builtin_bit_cast(short8, af);
#pragma unroll
      for (int dt = 0; dt < 4; ++dt){
        const short8 vb = *(const short8*)(Vh + (size_t)(dt * 16 + lr) * 1024 + kwbase + u * 32 + lg * 8);
        oacc[dt] = MFMA16(pa, vb, oacc[dt]);
      }
    }
  }
  // ---- denominator + cross-wave O reduce ----
  float d1 = esum + sxor(esum, 16);
  const float dq = d1 + sxor(d1, 32);
  if (l < 16) dsumL[w * 16 + l] = dq;
#pragma unroll
  for (int dt = 0; dt < 4; ++dt)
#pragma unroll
    for (int r = 0; r < 4; ++r)
      opart[w * 1024 + (lg * 4 + r) * 64 + dt * 16 + lr] = oacc[dt][r];
  __syncthreads();
  {
    const int qq = tid >> 4;
    const int d0 = (tid & 15) << 2;
    const float inv = rcpfast(dsumL[qq] + dsumL[16 + qq] + dsumL[32 + qq] + dsumL[48 + qq]);
    float o[4];
#pragma unroll
    for (int i = 0; i < 4; ++i){
      const int off = qq * 64 + d0 + i;
      o[i] = ((opart[off] + opart[1024 + off]) + (opart[2048 + off] + opart[3072 + off])) * inv;
    }
    uint2 pk2o;
    pk2o.x = cvtpk(o[0], o[1]);
    pk2o.y = cvtpk(o[2], o[3]);
    *(uint2*)&Ob[((size_t)(b * 1024 + q0 + qq)) * 1024 + h * 64 + d0] = pk2o;
  }
}

extern "C" void kernel_launch(void* const* d_in, const int* in_sizes, int n_in,
                              void* d_out, int out_size, void* d_ws, size_t ws_size,
                              hipStream_t stream) {
  const float* q    = (const float*)d_in[0];
  const float* k    = (const float*)d_in[1];
  const float* v    = (const float*)d_in[2];
  const float* Wq_w = (const float*)d_in[3];
  const float* Wq_b = (const float*)d_in[4];
  const float* Wk_w = (const float*)d_in[5];
  const float* Wk_b = (const float*)d_in[6];
  const float* Wv_w = (const float*)d_in[7];
  const float* Wv_b = (const float*)d_in[8];
  const float* Wo_w = (const float*)d_in[9];
  const float* Wo_b = (const float*)d_in[10];
  const float* pe   = (const float*)d_in[11];
  float* out = (float*)d_out;

  char* W = (char*)d_ws;
  const size_t MB = (size_t)1 << 20;
  us* Qbf = (us*)(W);
  us* Kbf = (us*)(W + 8 * MB);
  us* Vbf = (us*)(W + 16 * MB);
  us* VTb = (us*)(W + 24 * MB);
  us* Obf = (us*)(W + 32 * MB);
  us* peT = (us*)(W + 40 * MB);

  transpose_pe<<<1, 256, 0, stream>>>(pe, peT);
  gemm3<false, true><<<dim3(256, 3), 256, 0, stream>>>(
      q, k, v, Wq_w, Wk_w, Wv_w, Wq_b, Wk_b, Wv_b, Qbf, Kbf, Vbf);
  transpose_v<<<1024, 256, 0, stream>>>(Vbf, VTb);
  cope_attn_v14<<<4096, 256, 0, stream>>>(Qbf, Kbf, VTb, peT, Obf);
  gemm3<true, false><<<dim3(256, 1), 256, 0, stream>>>(
      Obf, Obf, Obf, Wo_w, Wo_w, Wo_w, Wo_b, Wo_b, Wo_b, out, out, out);
}

// Round 17
// 213.911 us; speedup vs baseline: 1.0340x; 1.0340x over previous
//
#include <hip/hip_runtime.h>
#include <hip/hip_bf16.h>

typedef __attribute__((ext_vector_type(8))) short short8;
typedef __attribute__((ext_vector_type(4))) float f32x4;
typedef unsigned short us;

#define MFMA16(a,b,c) __builtin_amdgcn_mfma_f32_16x16x32_bf16((a),(b),(c),0,0,0)
#define LOG2E 1.4426950408889634f

static __device__ __forceinline__ us bf16r(float x){
  unsigned u = __builtin_bit_cast(unsigned, x);
  u = u + 0x7fffu + ((u >> 16) & 1u);
  return (us)(u >> 16);
}
static __device__ __forceinline__ unsigned cvtpk(float a, float b){
  unsigned r; asm("v_cvt_pk_bf16_f32 %0, %1, %2" : "=v"(r) : "v"(a), "v"(b)); return r;
}
static __device__ __forceinline__ short8 cvt8(float4 a, float4 b){
  uint4 u; u.x = cvtpk(a.x, a.y); u.y = cvtpk(a.z, a.w);
  u.z = cvtpk(b.x, b.y); u.w = cvtpk(b.z, b.w);
  return __builtin_bit_cast(short8, u);
}
static __device__ __forceinline__ float b2f(us h){
  return __builtin_bit_cast(float, (unsigned)h << 16);
}
static __device__ __forceinline__ float PKLO(unsigned u){
  return __builtin_bit_cast(float, u << 16);
}
static __device__ __forceinline__ float PKHI(unsigned u){
  return __builtin_bit_cast(float, u & 0xffff0000u);
}
static __device__ __forceinline__ float exp2fast(float x){
  float r; asm("v_exp_f32 %0, %1" : "=v"(r) : "v"(x)); return r;
}
static __device__ __forceinline__ float rcpfast(float x){
  float r; asm("v_rcp_f32 %0, %1" : "=v"(r) : "v"(x)); return r;
}
static __device__ __forceinline__ float fractfast(float x){
  float r; asm("v_fract_f32 %0, %1" : "=v"(r) : "v"(x)); return r;
}
template<int CTRL, int RMASK>
static __device__ __forceinline__ float dpp_add(float x){
  int t = __builtin_amdgcn_update_dpp(0, __builtin_bit_cast(int, x), CTRL, RMASK, 0xf, false);
  return x + __builtin_bit_cast(float, t);
}
static __device__ __forceinline__ float wave_iscan(float x){
  x = dpp_add<0x111, 0xf>(x);
  x = dpp_add<0x112, 0xf>(x);
  x = dpp_add<0x114, 0xf>(x);
  x = dpp_add<0x118, 0xf>(x);
  x = dpp_add<0x142, 0xa>(x);
  x = dpp_add<0x143, 0xc>(x);
  return x;
}
static __device__ __forceinline__ float lane63(float x){
  return __builtin_bit_cast(float, __builtin_amdgcn_readlane(__builtin_bit_cast(int, x), 63));
}

// ---------------- pos_emb [64d][64n] fp32 -> peT [64n][64d] bf16, pre-scaled by log2(e) ----
__global__ __launch_bounds__(256)
void transpose_pe(const float* __restrict__ pe, us* __restrict__ peT){
  const int t = threadIdx.x;
  const int n = t & 63, dq = t >> 6;
#pragma unroll
  for (int j = 0; j < 16; ++j){
    const int d = dq * 16 + j;
    peT[n * 64 + d] = bf16r(pe[d * 64 + n] * LOG2E);
  }
}

// ---------------- GEMM: C[4096][1024] = A[4096][1024] @ W[1024][1024]^T + bias ----------
// VTo != nullptr && sel==2: write V transposed [b][h][64d][1024s] directly (fused transpose_v).
template<bool A_BF16, bool OUT_BF16>
__global__ __launch_bounds__(256)
void gemm3(const void* __restrict__ Av0, const void* __restrict__ Av1, const void* __restrict__ Av2,
           const float* __restrict__ W0, const float* __restrict__ W1, const float* __restrict__ W2,
           const float* __restrict__ bp0, const float* __restrict__ bp1, const float* __restrict__ bp2,
           void* __restrict__ O0, void* __restrict__ O1, void* __restrict__ O2,
           us* __restrict__ VTo){
  __shared__ __align__(16) us Al[128 * 64];
  __shared__ __align__(16) us Bl[128 * 64];
  const int sel = blockIdx.y;
  const void* Av   = sel == 0 ? Av0 : (sel == 1 ? Av1 : Av2);
  const float* Wm  = sel == 0 ? W0  : (sel == 1 ? W1  : W2);
  const float* bias = sel == 0 ? bp0 : (sel == 1 ? bp1 : bp2);
  void* Ov         = sel == 0 ? O0  : (sel == 1 ? O1  : O2);
  const int tid = threadIdx.x;
  const int bm = blockIdx.x & 31, bn = blockIdx.x >> 5;
  const int m0 = bm << 7, n0 = bn << 7;
  const int w = tid >> 6, l = tid & 63;
  const int lr = l & 15, lg = l >> 4;
  const int wm = (w & 1) << 6, wn = (w >> 1) << 6;
  int srow[4], scol[4], sdst[4];
#pragma unroll
  for (int c = 0; c < 4; ++c){
    const int idx = tid + (c << 8);
    const int r = idx >> 3, cw = idx & 7;
    srow[c] = r; scol[c] = cw << 3;
    sdst[c] = r * 64 + ((cw << 3) ^ ((r & 7) << 3));
  }
  const int swz = (lr & 7) << 3;
  f32x4 acc[4][4];
#pragma unroll
  for (int i = 0; i < 4; ++i)
#pragma unroll
    for (int j = 0; j < 4; ++j) acc[i][j] = (f32x4){0.f, 0.f, 0.f, 0.f};

  auto ldA = [&](int c, int k) -> short8 {
    if constexpr (A_BF16){
      return *(const short8*)((const us*)Av + (size_t)(m0 + srow[c]) * 1024 + k + scol[c]);
    } else {
      const float* p = (const float*)Av + (size_t)(m0 + srow[c]) * 1024 + k + scol[c];
      return cvt8(*(const float4*)p, *(const float4*)(p + 4));
    }
  };
  auto ldW = [&](int c, int k) -> short8 {
    const float* p = Wm + (size_t)(n0 + srow[c]) * 1024 + k + scol[c];
    return cvt8(*(const float4*)p, *(const float4*)(p + 4));
  };

  short8 av[4], bv[4];
#pragma unroll
  for (int c = 0; c < 4; ++c){ av[c] = ldA(c, 0); bv[c] = ldW(c, 0); }

  for (int k0 = 0; k0 < 1024; k0 += 64){
    __syncthreads();
#pragma unroll
    for (int c = 0; c < 4; ++c){
      *(short8*)&Al[sdst[c]] = av[c];
      *(short8*)&Bl[sdst[c]] = bv[c];
    }
    __syncthreads();
    if (k0 < 960){
#pragma unroll
      for (int c = 0; c < 4; ++c){ av[c] = ldA(c, k0 + 64); bv[c] = ldW(c, k0 + 64); }
    }
#pragma unroll
    for (int ks = 0; ks < 2; ++ks){
      short8 af[4], bfv[4];
#pragma unroll
      for (int mt = 0; mt < 4; ++mt)
        af[mt] = *(const short8*)&Al[(wm + mt * 16 + lr) * 64 + (((ks << 5) + (lg << 3)) ^ swz)];
#pragma unroll
      for (int nt = 0; nt < 4; ++nt)
        bfv[nt] = *(const short8*)&Bl[(wn + nt * 16 + lr) * 64 + (((ks << 5) + (lg << 3)) ^ swz)];
#pragma unroll
      for (int mt = 0; mt < 4; ++mt)
#pragma unroll
        for (int nt = 0; nt < 4; ++nt)
          acc[mt][nt] = MFMA16(af[mt], bfv[nt], acc[mt][nt]);
    }
  }
  float bb[4];
#pragma unroll
  for (int nt = 0; nt < 4; ++nt) bb[nt] = bias[n0 + wn + nt * 16 + lr];
  if (VTo != nullptr && sel == 2){
    // fused V-transpose epilogue: 4 consecutive s per acc tile -> one uint2 store
#pragma unroll
    for (int mt = 0; mt < 4; ++mt)
#pragma unroll
      for (int nt = 0; nt < 4; ++nt){
        const int n = n0 + wn + nt * 16 + lr;
        const int hh = n >> 6, dd = n & 63;
        const int mS = m0 + wm + mt * 16 + lg * 4;
        const int bb2 = mS >> 10, ss = mS & 1023;
        uint2 pk;
        pk.x = cvtpk(acc[mt][nt][0] + bb[nt], acc[mt][nt][1] + bb[nt]);
        pk.y = cvtpk(acc[mt][nt][2] + bb[nt], acc[mt][nt][3] + bb[nt]);
        *(uint2*)&VTo[((size_t)((bb2 * 16 + hh) * 64 + dd)) * 1024 + ss] = pk;
      }
    return;
  }
#pragma unroll
  for (int mt = 0; mt < 4; ++mt)
#pragma unroll
    for (int nt = 0; nt < 4; ++nt)
#pragma unroll
      for (int r = 0; r < 4; ++r){
        const size_t m = m0 + wm + mt * 16 + lg * 4 + r;
        const size_t n = n0 + wn + nt * 16 + lr;
        const float vv = acc[mt][nt][r] + bb[nt];
        if (OUT_BF16) ((us*)Ov)[m * 1024 + n] = bf16r(vv);
        else          ((float*)Ov)[m * 1024 + n] = vv;
      }
}

// ---------------- fused CoPE attention v15: v13 + packed u32 transit layout ------
// QK^T writes u32 {q-even,q-odd} pairs -> [8 pair][512 k] (2 b32/tile, was 4 b16);
// CoPE reads 4 b128/wave (was 8), unpacks 2 rows per u32; P written back as 4
// swizzled b128 (was 8) into [16 q][512 k] bf16 over the same wave-local region.
__global__ __launch_bounds__(256, 4)
void cope_attn_v15(const us* __restrict__ Qb, const us* __restrict__ Kb,
                   const us* __restrict__ VT, const us* __restrict__ peT,
                   us* __restrict__ Ob){
  __shared__ __align__(16) unsigned uls[8 * 512];   // 16 KB transit/P union
  __shared__ float sums[16];
  us* yl16 = (us*)uls;
  char* ybytes = (char*)uls;
  const int tid = threadIdx.x;
  const int w = tid >> 6, l = tid & 63;
  const int lr = l & 15, lg = l >> 4;
  const int wg = ((blockIdx.x & 7) << 9) | (blockIdx.x >> 3);  // XCD swizzle
  const int qt = wg & 63;
  const int bh = wg >> 6;
  const int b = bh >> 4, h = bh & 15;
  const int q0 = qt << 4;
  const us* Qh = Qb + ((size_t)(b * 1024 + q0)) * 1024 + h * 64;
  const us* Kh = Kb + ((size_t)(b * 1024)) * 1024 + h * 64;
  const us* Vh = VT + ((size_t)bh) * 64 * 1024;
  const float QSC = 0.125f * LOG2E;
  const f32x4 zf = (f32x4){0.f, 0.f, 0.f, 0.f};

  const short8 aq0 = *(const short8*)(Qh + (size_t)lr * 1024 + lg * 8);
  const short8 aq1 = *(const short8*)(Qh + (size_t)lr * 1024 + 32 + lg * 8);

  // 1) li[q][n] = (Q . pos_emb)*log2e ; wave w owns n-tile [16w,16w+16) -> bf16 temp
  {
    f32x4 a = zf;
    const short8 p0 = *(const short8*)(peT + (size_t)(w * 16 + lr) * 64 + lg * 8);
    const short8 p1 = *(const short8*)(peT + (size_t)(w * 16 + lr) * 64 + 32 + lg * 8);
    a = MFMA16(aq0, p0, a);
    a = MFMA16(aq1, p1, a);
#pragma unroll
    for (int r = 0; r < 4; ++r) yl16[(lg * 4 + r) * 64 + w * 16 + lr] = bf16r(a[r]);
  }
  __syncthreads();
  // 2) per-row register tables: lane n holds {li[n] (lo16), li[n+1]-li[n] (hi16)}
  unsigned trow[4];
#pragma unroll
  for (int rr = 0; rr < 4; ++rr){
    const int row = w * 4 + rr;
    const us lov = yl16[row * 64 + l];
    const us hiv = (l < 63) ? yl16[row * 64 + l + 1] : lov;
    const float dif = b2f(hiv) - b2f(lov);
    trow[rr] = (unsigned)lov | ((unsigned)bf16r(dif) << 16);
  }

  float carry[4] = {0.f, 0.f, 0.f, 0.f};
  f32x4 oacc = (f32x4){0.f, 0.f, 0.f, 0.f};
  const int d0 = w * 16;
  const int psw = lr & 7;

  for (int c = 1; c >= 0; --c){
    const int koff = c << 9;
    __syncthreads();   // uls free
    // 3) QK^T -> packed u32 transit [pair][k]; wave keys [128w,128w+128)
    {
      const int kbase = w << 7;
      const us* Kw = Kh + (size_t)(koff + kbase + lr) * 1024 + lg * 8;
      for (int t = 0; t < 8; ++t){
        const short8 b0 = *(const short8*)(Kw + (size_t)(t * 16) * 1024);
        const short8 b1 = *(const short8*)(Kw + (size_t)(t * 16) * 1024 + 32);
        f32x4 a = zf;
        a = MFMA16(aq0, b0, a);
        a = MFMA16(aq1, b1, a);
        const int kc = kbase + t * 16 + lr;
        uls[(lg * 2) * 512 + kc]     = cvtpk(a[0] * QSC, a[1] * QSC);
        uls[(lg * 2 + 1) * 512 + kc] = cvtpk(a[2] * QSC, a[3] * QSC);
      }
    }
    __syncthreads();
    // 4) CoPE: wave owns pairs {2w,2w+1} = q rows 4w..4w+3; lane owns k [8l,8l+8)
#pragma unroll
    for (int pp = 0; pp < 2; ++pp){
      const int pr = w * 2 + pp;
      const uint4 ra = *(const uint4*)&uls[pr * 512 + l * 8];
      const uint4 rb = *(const uint4*)&uls[pr * 512 + l * 8 + 4];
#pragma unroll
      for (int par = 0; par < 2; ++par){
        const int rr = pp * 2 + par;
        const int row = w * 4 + rr;
        float x[8];
        if (par == 0){
          x[0] = PKLO(ra.x); x[1] = PKLO(ra.y); x[2] = PKLO(ra.z); x[3] = PKLO(ra.w);
          x[4] = PKLO(rb.x); x[5] = PKLO(rb.y); x[6] = PKLO(rb.z); x[7] = PKLO(rb.w);
        } else {
          x[0] = PKHI(ra.x); x[1] = PKHI(ra.y); x[2] = PKHI(ra.z); x[3] = PKHI(ra.w);
          x[4] = PKHI(rb.x); x[5] = PKHI(rb.y); x[6] = PKHI(rb.z); x[7] = PKHI(rb.w);
        }
        float sum = 0.f;
        if (c == 0 && carry[rr] >= 63.f){
          const float li63 = b2f((us)(unsigned)__builtin_amdgcn_readlane((int)trow[rr], 63));
#pragma unroll
          for (int i = 0; i < 8; ++i){
            const float e = exp2fast(x[i] + li63);
            x[i] = e;
            sum += e;
          }
        } else {
          float g[8];
#pragma unroll
          for (int i = 0; i < 8; ++i) g[i] = rcpfast(1.f + exp2fast(-x[i]));
          const float a1 = g[0] + g[1];
          const float a3 = g[2] + g[3];
          const float a5 = g[4] + g[5];
          const float a7 = g[6] + g[7];
          const float b2v = g[2] + a1;
          const float b3v = a3 + a1;
          const float i4 = g[4] + b3v;
          const float i5 = a5 + b3v;
          const float i6 = g[6] + a5 + b3v;
          const float s  = a7 + a5 + b3v;
          float pref[8];
          pref[0] = 0.f;  pref[1] = g[0]; pref[2] = a1;  pref[3] = b2v;
          pref[4] = b3v;  pref[5] = i4;   pref[6] = i5;  pref[7] = i6;
          const float run = wave_iscan(s);
          const float T = lane63(run);
          const float base = carry[rr] + T - (run - s);
          carry[rr] += T;
          const unsigned tbl = trow[rr];
#pragma unroll
          for (int i = 0; i < 8; ++i){
            float p = base - pref[i];
            p = __builtin_amdgcn_fmed3f(p, 0.f, 63.f);
            const int il = (int)p;
            const float wt = fractfast(p);
            const unsigned pr2 = (unsigned)__builtin_amdgcn_ds_bpermute(il << 2, (int)tbl);
            const float lo  = __builtin_bit_cast(float, pr2 << 16);
            const float dif = __builtin_bit_cast(float, pr2 & 0xffff0000u);
            const float e = exp2fast(x[i] + lo + wt * dif);
            x[i] = e;
            sum += e;
          }
        }
        const float rs = lane63(wave_iscan(sum));
        if (l == 0){
          if (c == 1) sums[row] = rs;
          else        sums[row] += rs;
        }
        // P write: [q][k] bf16, granule-XOR swizzle; wave-local region (in-order safe)
        uint4 ua;
        ua.x = cvtpk(x[0], x[1]); ua.y = cvtpk(x[2], x[3]);
        ua.z = cvtpk(x[4], x[5]); ua.w = cvtpk(x[6], x[7]);
        *(uint4*)(ybytes + row * 1024 + ((l ^ (row & 7)) << 4)) = ua;
      }
    }
    __syncthreads();
    // 5) PV accumulate: wave w owns d-tile [16w,16w+16)
    {
      const us* Vw = Vh + (size_t)(d0 + lr) * 1024 + koff + lg * 8;
      for (int ks = 0; ks < 16; ++ks){
        const short8 vb = *(const short8*)(Vw + ks * 32);
        const short8 pa = *(const short8*)(ybytes + lr * 1024 + ((((ks << 2) + lg) ^ psw) << 4));
        oacc = MFMA16(pa, vb, oacc);
      }
    }
  }
  __syncthreads();   // sums visible
#pragma unroll
  for (int r = 0; r < 4; ++r){
    const float inv = rcpfast(sums[lg * 4 + r]);
    Ob[((size_t)(b * 1024 + q0 + lg * 4 + r)) * 1024 + h * 64 + d0 + lr] = bf16r(oacc[r] * inv);
  }
}

extern "C" void kernel_launch(void* const* d_in, const int* in_sizes, int n_in,
                              void* d_out, int out_size, void* d_ws, size_t ws_size,
                              hipStream_t stream) {
  const float* q    = (const float*)d_in[0];
  const float* k    = (const float*)d_in[1];
  const float* v    = (const float*)d_in[2];
  const float* Wq_w = (const float*)d_in[3];
  const float* Wq_b = (const float*)d_in[4];
  const float* Wk_w = (const float*)d_in[5];
  const float* Wk_b = (const float*)d_in[6];
  const float* Wv_w = (const float*)d_in[7];
  const float* Wv_b = (const float*)d_in[8];
  const float* Wo_w = (const float*)d_in[9];
  const float* Wo_b = (const float*)d_in[10];
  const float* pe   = (const float*)d_in[11];
  float* out = (float*)d_out;

  char* W = (char*)d_ws;
  const size_t MB = (size_t)1 << 20;
  us* Qbf = (us*)(W);
  us* Kbf = (us*)(W + 8 * MB);
  us* Vbf = (us*)(W + 16 * MB);
  us* VTb = (us*)(W + 24 * MB);
  us* Obf = (us*)(W + 32 * MB);
  us* peT = (us*)(W + 40 * MB);

  transpose_pe<<<1, 256, 0, stream>>>(pe, peT);
  gemm3<false, true><<<dim3(256, 3), 256, 0, stream>>>(
      q, k, v, Wq_w, Wk_w, Wv_w, Wq_b, Wk_b, Wv_b, Qbf, Kbf, Vbf, VTb);
  cope_attn_v15<<<4096, 256, 0, stream>>>(Qbf, Kbf, VTb, peT, Obf);
  gemm3<true, false><<<dim3(256, 1), 256, 0, stream>>>(
      Obf, Obf, Obf, Wo_w, Wo_w, Wo_w, Wo_b, Wo_b, Wo_b, out, out, out, nullptr);
}